// Round 6
// baseline (205.595 us; speedup 1.0000x reference)
//
#include <hip/hip_runtime.h>
#include <stdint.h>

typedef __attribute__((ext_vector_type(8))) short short8;
typedef __attribute__((ext_vector_type(4))) float floatx4;

#define AS1 __attribute__((address_space(1)))
#define AS3 __attribute__((address_space(3)))

__device__ __forceinline__ void gld16(const void* g, void* l) {
  __builtin_amdgcn_global_load_lds((AS1 const void*)g, (AS3 void*)l, 16, 0, 0);
}

__device__ __forceinline__ unsigned short f2bf(float f) {
  unsigned int u = __float_as_uint(f);
  return (unsigned short)((u + 0x7fffu + ((u >> 16) & 1u)) >> 16);
}

// ---------------------------------------------------------------------------
// k_pre: blocks [0,512) = featT (X0[p][c] = bf16 feat, pixel-major 128B rows);
// blocks [512,...) = weight packing into MFMA A-fragment order.
// W0=30 is FOLDED into wp0..wp3 and b0p/b1p/b2p/b3p (sin(30*(Wx+b)) ==
// sin((30W)x + 30b)), so the epilogue computes sin(acc) directly.
// Packed: per (panel of 16 out-features, step) one 1KB chunk, element (lane,j)
// at chunk + lane*16 + j*2 -> feature = panel*16 + (lane&15),
// k = kk*32 + (lane>>4)*8 + j.  Every af load = coalesced 1KB burst.
// wp0: 16 panels x 18 steps(tap*2+kk);  wp{1,2,3}: 16 panels x 8 kk;
// wp4: 2 panels x 8 kk (feature>=27 -> 0, unscaled).
// b0p[n] = 30*(b0[n] + t*w0[576*256+n]);  b{1,2,3}p = 30*b;  b4p padded to 32.
// Bias region is 768 elems (e < 353312), grid 1893 (round-3 bug fix).
// ---------------------------------------------------------------------------
__global__ __launch_bounds__(256) void k_pre(
    const float* __restrict__ feat,
    const float* __restrict__ w0, const float* __restrict__ b0,
    const float* __restrict__ w1, const float* __restrict__ b1,
    const float* __restrict__ w2, const float* __restrict__ b2,
    const float* __restrict__ w3, const float* __restrict__ b3,
    const float* __restrict__ w4, const float* __restrict__ b4,
    const float* __restrict__ coord,
    unsigned short* __restrict__ X0,
    unsigned short* __restrict__ wp0, unsigned short* __restrict__ wp1,
    unsigned short* __restrict__ wp2, unsigned short* __restrict__ wp3,
    unsigned short* __restrict__ wp4, float* __restrict__ b0p,
    float* __restrict__ b4p, float* __restrict__ b1p,
    float* __restrict__ b2p, float* __restrict__ b3p) {
  const int bid = blockIdx.x;
  const int tid = threadIdx.x;
  if (bid < 512) {
    const int p = bid * 256 + tid;
    const int b = p >> 16;
    const int off = p & 65535;
    const float* src = feat + ((int64_t)b << 22) + off;
    unsigned int tw[32];
#pragma unroll
    for (int c = 0; c < 32; ++c) {
      float lo = src[(int64_t)(2 * c) << 16];
      float hi = src[(int64_t)(2 * c + 1) << 16];
      tw[c] = (unsigned int)f2bf(lo) | ((unsigned int)f2bf(hi) << 16);
    }
    uint4* dst = (uint4*)(X0 + (int64_t)p * 64);
#pragma unroll
    for (int k = 0; k < 8; ++k) {
      uint4 v;
      v.x = tw[4 * k]; v.y = tw[4 * k + 1]; v.z = tw[4 * k + 2]; v.w = tw[4 * k + 3];
      dst[k] = v;
    }
    return;
  }
  const int e = (bid - 512) * 256 + tid;
  if (e < 147456) {
    const int j = e & 7, lane = (e >> 3) & 63, r = e >> 9;
    const int kk = r & 1, s = r >> 1;
    const int tap = s % 9, panel = s / 9;
    const int feature = panel * 16 + (lane & 15);
    const int c = kk * 32 + (lane >> 4) * 8 + j;
    wp0[e] = f2bf(30.0f * w0[(c * 9 + tap) * 256 + feature]);
  } else if (e < 344064) {
    const int e2 = e - 147456;
    const int l = e2 >> 16;
    const int u = e2 & 65535;
    const int j = u & 7, lane = (u >> 3) & 63, kk = (u >> 9) & 7, panel = (u >> 12) & 15;
    const int feature = panel * 16 + (lane & 15);
    const int k = kk * 32 + (lane >> 4) * 8 + j;
    const float* w = (l == 0) ? w1 : (l == 1) ? w2 : w3;
    unsigned short* wt = (l == 0) ? wp1 : (l == 1) ? wp2 : wp3;
    wt[u] = f2bf(30.0f * w[k * 256 + feature]);
  } else if (e < 352256) {
    const int u = e - 344064;
    const int j = u & 7, lane = (u >> 3) & 63, kk = (u >> 9) & 7, i = (u >> 12) & 1;
    const int feature = i * 16 + (lane & 15);
    const int k = kk * 32 + (lane >> 4) * 8 + j;
    wp4[u] = (feature < 27) ? f2bf(w4[k * 27 + feature]) : (unsigned short)0;
  } else if (e < 352512) {
    const int n = e - 352256;
    b0p[n] = 30.0f * (b0[n] + coord[2] * w0[576 * 256 + n]);
  } else if (e < 352544) {
    const int n = e - 352512;
    b4p[n] = (n < 27) ? b4[n] : 0.0f;
  } else if (e < 353312) {
    const int n = e - 352544;  // 0..767
    const int l = n >> 8;
    const int m = n & 255;
    const float* bs = (l == 0) ? b1 : (l == 1) ? b2 : b3;
    float* bd = (l == 0) ? b1p : (l == 1) ? b2p : b3p;
    bd[m] = 30.0f * bs[m];
  }
}

// ---------------------------------------------------------------------------
// Fused MLP. Block = 64 pixels, 4 waves, H = 32KB in-place -> 3 blocks/CU
// (96KB LDS, 12 waves/CU).  __launch_bounds__(256,3): 168-reg budget/wave;
// accA+accB = 64 AGPR + ~84 arch VGPR, zero spill target (round-4 verified).
// ROUND-6: px-half software pipeline.  H is px-major, so a wave's acc for
// px-half A completes after reading only half-A of H.  Per mid layer:
//   P1: midK(half A) fused with retire-epilogue of the PREVIOUS half-B acc
//       (sin+pack -> H half B); barrier;
//   P2: midK(half B) fused with retire-epilogue of this layer's half-A acc;
//       barrier.
// Reads and epi-writes in a phase touch DISJOINT H halves for all waves ->
// race-free, same barrier count as before, but the bare-VALU epilogue phases
// (4 x ~2k cyc/wave) are now hidden in the MFMA phases' spare issue slots.
// Only act1-halfA (pipeline fill) and act4-halfB (drain) epilogues are bare.
// Round-5's bar_lds + setprio are REVERTED (measured -12us: asm memory
// clobbers + per-cluster setprio cut compiler prefetch depth, VGPR 84->68).
// A = packed weights (1KB coalesced L2-hit bursts), B = activations (LDS).
// H layout: px-major 512B/px, chunk c at px*512 + ((c^(px&7))<<4).
// Layer-0 patch: 3 rows x 66 px x 128B = 24.75KB aliases H.
// XCD-chunked swizzle: 2048 blocks %8==0 -> bijective.
// pat is plane-major: pat[g*131072 + p], g=0..26.
// ---------------------------------------------------------------------------
__device__ __forceinline__ void acc_init_half(floatx4 (&acc)[4][2],
                                              const float* __restrict__ bias,
                                              int wv, int q) {
#pragma unroll
  for (int i = 0; i < 4; ++i) {
    const float4 bv = *(const float4*)(bias + wv * 64 + i * 16 + q * 4);
    floatx4 a;
    a[0] = bv.x; a[1] = bv.y; a[2] = bv.z; a[3] = bv.w;
    acc[i][0] = a; acc[i][1] = a;
  }
}

// midK over px-half HALF, accumulating into acc; if DOEPI, retire accOld
// (finished pre-activations of the OTHER px-half) into H's other half,
// one [i][j2] chunk per kk step (8 chunks == 8 kk steps).
template <int HALF, bool DOEPI>
__device__ __forceinline__ void midK_half(floatx4 (&acc)[4][2],
                                          floatx4 (&accOld)[4][2],
                                          char* H, const unsigned short* WT,
                                          int wv, int lm, int q, int ln16) {
  const char* a0 = (const char*)WT + wv * 32768 + ln16;
  const int l7 = lm & 7;
#pragma unroll
  for (int kk = 0; kk < 8; ++kk) {
    short8 af[4];
#pragma unroll
    for (int i = 0; i < 4; ++i)
      af[i] = *(const short8*)(a0 + ((i * 8 + kk) << 10));
#pragma unroll
    for (int j2 = 0; j2 < 2; ++j2) {
      const int pp = (HALF * 2 + j2) * 16 + lm;
      const int c = kk * 4 + q;
      const short8 bfr = *(const short8*)(H + pp * 512 + ((c ^ l7) << 4));
#pragma unroll
      for (int i = 0; i < 4; ++i)
        acc[i][j2] = __builtin_amdgcn_mfma_f32_16x16x32_bf16(af[i], bfr, acc[i][j2], 0, 0, 0);
    }
    if constexpr (DOEPI) {
      const int io = kk >> 1;      // compile-time (kk unrolled)
      const int j2o = kk & 1;
      const int jo = (1 - HALF) * 2 + j2o;
      unsigned int lo = (unsigned int)f2bf(__sinf(accOld[io][j2o][0]))
                      | ((unsigned int)f2bf(__sinf(accOld[io][j2o][1])) << 16);
      unsigned int hi = (unsigned int)f2bf(__sinf(accOld[io][j2o][2]))
                      | ((unsigned int)f2bf(__sinf(accOld[io][j2o][3])) << 16);
      const int ppo = jo * 16 + lm;
      const int co = wv * 8 + io * 2 + (q >> 1);
      uint2 v; v.x = lo; v.y = hi;
      *(uint2*)(H + ppo * 512 + ((co ^ l7) << 4) + (q & 1) * 8) = v;
    }
  }
}

// bare half-epilogue (pipeline fill/drain)
template <int HALF>
__device__ __forceinline__ void epi_half(floatx4 (&acc)[4][2], char* Hout,
                                         int wv, int lm, int q) {
  const int l7 = lm & 7;
#pragma unroll
  for (int i = 0; i < 4; ++i) {
#pragma unroll
    for (int j2 = 0; j2 < 2; ++j2) {
      unsigned int lo = (unsigned int)f2bf(__sinf(acc[i][j2][0]))
                      | ((unsigned int)f2bf(__sinf(acc[i][j2][1])) << 16);
      unsigned int hi = (unsigned int)f2bf(__sinf(acc[i][j2][2]))
                      | ((unsigned int)f2bf(__sinf(acc[i][j2][3])) << 16);
      const int pp = (HALF * 2 + j2) * 16 + lm;
      const int c = wv * 8 + i * 2 + (q >> 1);
      uint2 v; v.x = lo; v.y = hi;
      *(uint2*)(Hout + pp * 512 + ((c ^ l7) << 4) + (q & 1) * 8) = v;
    }
  }
}

__global__ __launch_bounds__(256, 3) void k_fused(
    const unsigned short* __restrict__ X0,
    const unsigned short* __restrict__ wp0, const float* __restrict__ b0p,
    const unsigned short* __restrict__ wp1, const float* __restrict__ b1,
    const unsigned short* __restrict__ wp2, const float* __restrict__ b2,
    const unsigned short* __restrict__ wp3, const float* __restrict__ b3,
    const unsigned short* __restrict__ wp4, const float* __restrict__ b4p,
    float* __restrict__ pat) {
  __shared__ alignas(128) char H[32768];
  const int tid = threadIdx.x;
  const int bid = ((blockIdx.x & 7) << 8) + (blockIdx.x >> 3);  // XCD chunk
  const int pbase = bid * 64;
  const int bimg = pbase >> 16;
  const int y = (pbase >> 8) & 255;
  const int x0 = pbase & 255;  // 0, 64, 128 or 192
  const int lm = tid & 15;
  const int q = (tid & 63) >> 4;
  const int wv = tid >> 6;
  const int l7 = lm & 7;
  const int ln16 = (tid & 63) * 16;

  // ---- stage 3x66 pixel patch (1584 chunks of 16B, swizzled by rp&7) ----
#pragma unroll
  for (int iter = 0; iter < 7; ++iter) {
    const int ci = iter * 256 + tid;
    if (ci < 1584) {
      const int rp = ci >> 3;
      const int row = rp / 66;
      const int col = rp - row * 66;
      int gy = y + row - 1;
      int gx = x0 + col - 1;
      gy = gy < 0 ? 0 : (gy > 255 ? 255 : gy);
      gx = gx < 0 ? 0 : (gx > 255 ? 255 : gx);
      const int gch = (ci & 7) ^ (rp & 7);
      const int p = (bimg << 16) + (gy << 8) + gx;
      gld16((const char*)X0 + (int64_t)p * 128 + gch * 16, H + ci * 16);
    }
  }
  __syncthreads();
  // zero out-of-range pixels (image edges)
#pragma unroll
  for (int iter = 0; iter < 7; ++iter) {
    const int ci = iter * 256 + tid;
    if (ci < 1584) {
      const int rp = ci >> 3;
      const int row = rp / 66;
      const int col = rp - row * 66;
      const int gy = y + row - 1;
      const int gx = x0 + col - 1;
      if ((unsigned)gy >= 256u || (unsigned)gx >= 256u) {
        uint4 z; z.x = 0; z.y = 0; z.z = 0; z.w = 0;
        *(uint4*)(H + ci * 16) = z;
      }
    }
  }
  __syncthreads();

  floatx4 accA[4][2];  // px-half A (j = 0,1)
  floatx4 accB[4][2];  // px-half B (j = 2,3)
  acc_init_half(accA, b0p, wv, q);
  acc_init_half(accB, b0p, wv, q);

  // ---- layer 0: implicit 3x3 conv, 18 (tap,kk) steps, both px halves ----
  {
    const char* a0 = (const char*)wp0 + wv * 73728 + ln16;
#pragma unroll
    for (int t = 0; t < 18; ++t) {
      short8 af[4];
#pragma unroll
      for (int i = 0; i < 4; ++i)
        af[i] = *(const short8*)(a0 + ((i * 18 + t) << 10));
      const int tap = t >> 1;
      const int kk = t & 1;
      const int dyr = tap / 3;
      const int dxr = tap - dyr * 3;
      const int rpb = dyr * 66 + dxr;
#pragma unroll
      for (int j = 0; j < 4; ++j) {
        const int rp = rpb + j * 16 + lm;
        const int c = kk * 4 + q;
        const short8 bfr = *(const short8*)(H + rp * 128 + ((c ^ (rp & 7)) << 4));
        if (j < 2) {
#pragma unroll
          for (int i = 0; i < 4; ++i)
            accA[i][j] = __builtin_amdgcn_mfma_f32_16x16x32_bf16(af[i], bfr, accA[i][j], 0, 0, 0);
        } else {
#pragma unroll
          for (int i = 0; i < 4; ++i)
            accB[i][j - 2] = __builtin_amdgcn_mfma_f32_16x16x32_bf16(af[i], bfr, accB[i][j - 2], 0, 0, 0);
        }
      }
    }
  }
  __syncthreads();             // patch fully read by all waves
  epi_half<0>(accA, H, wv, lm, q);   // act1 half A (pipeline fill, bare)
  __syncthreads();

  // ---- layers 1..3: px-half pipeline ----
  const unsigned short* WTs[3] = {wp1, wp2, wp3};
  const float* Bs[3] = {b1, b2, b3};
#pragma unroll 1
  for (int l = 0; l < 3; ++l) {
    // P1: compute half A of layer l output; retire half B of layer l input
    acc_init_half(accA, Bs[l], wv, q);
    midK_half<0, true>(accA, accB, H, WTs[l], wv, lm, q, ln16);
    __syncthreads();
    // P2: compute half B; retire half A of layer l output
    acc_init_half(accB, Bs[l], wv, q);
    midK_half<1, true>(accB, accA, H, WTs[l], wv, lm, q, ln16);
    __syncthreads();
  }
  epi_half<1>(accB, H, wv, lm, q);   // act4 half B (pipeline drain, bare)
  __syncthreads();

  // ---- layer 4: H -> pat planes (each wave: 16-px strip x 32 features) ----
  {
    floatx4 a4[2];
#pragma unroll
    for (int i = 0; i < 2; ++i) {
      const float4 bb = *(const float4*)(b4p + i * 16 + q * 4);
      floatx4 a;
      a[0] = bb.x; a[1] = bb.y; a[2] = bb.z; a[3] = bb.w;
      a4[i] = a;
    }
    const char* aw = (const char*)wp4 + ln16;
    const int pp = wv * 16 + lm;
#pragma unroll
    for (int kk = 0; kk < 8; ++kk) {
      const short8 af0 = *(const short8*)(aw + (kk << 10));
      const short8 af1 = *(const short8*)(aw + ((8 + kk) << 10));
      const int c = kk * 4 + q;
      const short8 bfr = *(const short8*)(H + pp * 512 + ((c ^ l7) << 4));
      a4[0] = __builtin_amdgcn_mfma_f32_16x16x32_bf16(af0, bfr, a4[0], 0, 0, 0);
      a4[1] = __builtin_amdgcn_mfma_f32_16x16x32_bf16(af1, bfr, a4[1], 0, 0, 0);
    }
#pragma unroll
    for (int i = 0; i < 2; ++i)
#pragma unroll
      for (int r = 0; r < 4; ++r) {
        const int g = i * 16 + q * 4 + r;
        if (g < 27)
          pat[g * 131072 + pbase + wv * 16 + lm] = a4[i][r];
      }
  }
}

// fold3 (plane-major pat): out[b][c][y][x] =
//   sum_{i,j} pat[(c*9+i*3+j)*131072 + b*65536 + (y+1-i)*256 + (x+1-j)]
__global__ __launch_bounds__(256) void k_fold(const float* __restrict__ pat,
                                              float* __restrict__ out) {
  const int e = blockIdx.x * 256 + threadIdx.x;  // < 393216
  const int x = e & 255;
  const int y = (e >> 8) & 255;
  const int bc = e >> 16;
  const int c = bc % 3;
  const int b = bc / 3;
  float s = 0.0f;
#pragma unroll
  for (int i = 0; i < 3; ++i) {
    const int yy = y + 1 - i;
    if (yy < 0 || yy > 255) continue;
#pragma unroll
    for (int j = 0; j < 3; ++j) {
      const int xx = x + 1 - j;
      if (xx < 0 || xx > 255) continue;
      s += pat[(c * 9 + i * 3 + j) * 131072 + (b << 16) + yy * 256 + xx];
    }
  }
  out[e] = s;
}

extern "C" void kernel_launch(void* const* d_in, const int* in_sizes, int n_in,
                              void* d_out, int out_size, void* d_ws, size_t ws_size,
                              hipStream_t stream) {
  const float* feat  = (const float*)d_in[0];
  const float* coord = (const float*)d_in[1];
  const float* w0 = (const float*)d_in[2];
  const float* b0 = (const float*)d_in[3];
  const float* w1 = (const float*)d_in[4];
  const float* b1 = (const float*)d_in[5];
  const float* w2 = (const float*)d_in[6];
  const float* b2 = (const float*)d_in[7];
  const float* w3 = (const float*)d_in[8];
  const float* b3 = (const float*)d_in[9];
  const float* w4 = (const float*)d_in[10];
  const float* b4 = (const float*)d_in[11];

  char* ws = (char*)d_ws;
  unsigned short* X0  = (unsigned short*)(ws);                 // 16.78 MB
  float*          pat = (float*)(ws + 16777216);               // 14.16 MB (27 planes)
  float*          b1p = (float*)(ws + 30932992);               // in pat..wp0 slack
  float*          b2p = (float*)(ws + 30934016);
  float*          b3p = (float*)(ws + 30935040);
  unsigned short* wp0 = (unsigned short*)(ws + 33554432);      // 294912 B
  unsigned short* wp1 = (unsigned short*)(ws + 33849344);      // 131072 B
  unsigned short* wp2 = (unsigned short*)(ws + 33980416);
  unsigned short* wp3 = (unsigned short*)(ws + 34111488);
  unsigned short* wp4 = (unsigned short*)(ws + 34242560);      // 16384 B
  float*          b0p = (float*)(ws + 34258944);               // 1024 B
  float*          b4p = (float*)(ws + 34259968);               // 128 B
  float* out = (float*)d_out;

  hipLaunchKernelGGL(k_pre, dim3(1893), dim3(256), 0, stream,
                     feat, w0, b0, w1, b1, w2, b2, w3, b3, w4, b4, coord,
                     X0, wp0, wp1, wp2, wp3, wp4, b0p, b4p, b1p, b2p, b3p);
  hipLaunchKernelGGL(k_fused, dim3(2048), dim3(256), 0, stream,
                     X0, wp0, b0p, wp1, b1p, wp2, b2p, wp3, b3p, wp4, b4p, pat);
  hipLaunchKernelGGL(k_fold, dim3(1536), dim3(256), 0, stream, pat, out);
}

// Round 7
// 198.109 us; speedup vs baseline: 1.0378x; 1.0378x over previous
//
#include <hip/hip_runtime.h>
#include <stdint.h>

typedef __attribute__((ext_vector_type(8))) short short8;
typedef __attribute__((ext_vector_type(4))) float floatx4;

#define AS1 __attribute__((address_space(1)))
#define AS3 __attribute__((address_space(3)))

__device__ __forceinline__ void gld16(const void* g, void* l) {
  __builtin_amdgcn_global_load_lds((AS1 const void*)g, (AS3 void*)l, 16, 0, 0);
}

__device__ __forceinline__ unsigned short f2bf(float f) {
  unsigned int u = __float_as_uint(f);
  return (unsigned short)((u + 0x7fffu + ((u >> 16) & 1u)) >> 16);
}

// ---------------------------------------------------------------------------
// k_pre (ROUND-7 restructure for coalescing; output bit-identical to round-4):
// blocks [0,1024): featT — block pair (pb,h): h selects channels 32h..32h+31
//   for pixel range pb*256..+255.  X0[p][c] = bf16 feat, pixel-major 128B
//   rows; each block writes the 64B half-row.  2x TLP vs round-4's 512 blocks.
// blocks [1024,1096): wp0   — 8 elems/thread: 16 consecutive lanes read
//   feature-consecutive w0 addrs = 64B contiguous per group per j (was: 8
//   consecutive threads at 9KB stride = 64 cache lines per wave-load).
// blocks [1096,1192): wp1-3 — same 8-per-thread scheme.
// blocks [1192,1196): wp4.
// block 1196: b0p; 1197: b4p; 1198-1200: b1p/b2p/b3p.
// W0=30 folded into wp0..wp3 and b0p..b3p (sin(30*(Wx+b)) == sin((30W)x+30b)).
// Packed layout: per (panel of 16 out-features, step) one 1KB chunk,
// element (lane,j) at chunk + lane*16 + j*2 -> feature = panel*16+(lane&15),
// k = kk*32 + (lane>>4)*8 + j.  Every af load in k_fused = 1KB burst.
// ---------------------------------------------------------------------------
__global__ __launch_bounds__(256) void k_pre(
    const float* __restrict__ feat,
    const float* __restrict__ w0, const float* __restrict__ b0,
    const float* __restrict__ w1, const float* __restrict__ b1,
    const float* __restrict__ w2, const float* __restrict__ b2,
    const float* __restrict__ w3, const float* __restrict__ b3,
    const float* __restrict__ w4, const float* __restrict__ b4,
    const float* __restrict__ coord,
    unsigned short* __restrict__ X0,
    unsigned short* __restrict__ wp0, unsigned short* __restrict__ wp1,
    unsigned short* __restrict__ wp2, unsigned short* __restrict__ wp3,
    unsigned short* __restrict__ wp4, float* __restrict__ b0p,
    float* __restrict__ b4p, float* __restrict__ b1p,
    float* __restrict__ b2p, float* __restrict__ b3p) {
  const int bid = blockIdx.x;
  const int tid = threadIdx.x;
  if (bid < 1024) {
    const int pb = bid >> 1;
    const int h = bid & 1;           // channel half: 32h..32h+31
    const int p = pb * 256 + tid;
    const int b = p >> 16;
    const int off = p & 65535;
    const float* src = feat + ((int64_t)b << 22) + ((int64_t)(h * 32) << 16) + off;
    unsigned int tw[16];
#pragma unroll
    for (int c = 0; c < 16; ++c) {
      float lo = src[(int64_t)(2 * c) << 16];
      float hi = src[(int64_t)(2 * c + 1) << 16];
      tw[c] = (unsigned int)f2bf(lo) | ((unsigned int)f2bf(hi) << 16);
    }
    uint4* dst = (uint4*)(X0 + (int64_t)p * 64 + h * 32);
#pragma unroll
    for (int k = 0; k < 4; ++k) {
      uint4 v;
      v.x = tw[4 * k]; v.y = tw[4 * k + 1]; v.z = tw[4 * k + 2]; v.w = tw[4 * k + 3];
      dst[k] = v;
    }
    return;
  }
  if (bid < 1096) {                  // wp0: 72 blocks x 256 thr x 8 el = 147456
    const int t = (bid - 1024) * 256 + tid;
    const int lane = t & 63;
    const int r = t >> 6;
    const int kk = r & 1, s = r >> 1;
    const int tap = s % 9, panel = s / 9;
    const int feature = panel * 16 + (lane & 15);
    const int cb = kk * 32 + (lane >> 4) * 8;
    unsigned int w[4];
#pragma unroll
    for (int j2 = 0; j2 < 4; ++j2) {
      const unsigned short e0 = f2bf(30.0f * w0[((cb + 2 * j2) * 9 + tap) * 256 + feature]);
      const unsigned short e1 = f2bf(30.0f * w0[((cb + 2 * j2 + 1) * 9 + tap) * 256 + feature]);
      w[j2] = (unsigned int)e0 | ((unsigned int)e1 << 16);
    }
    uint4 v; v.x = w[0]; v.y = w[1]; v.z = w[2]; v.w = w[3];
    *(uint4*)(wp0 + t * 8) = v;
    return;
  }
  if (bid < 1192) {                  // wp1-3: 96 blocks -> 24576 thr x 8 el
    const int t = (bid - 1096) * 256 + tid;
    const int l = t >> 13;           // matrix 0..2
    const int tt = t & 8191;
    const int lane = tt & 63;
    const int kk = (tt >> 6) & 7;
    const int panel = (tt >> 9) & 15;
    const int feature = panel * 16 + (lane & 15);
    const int kb = kk * 32 + (lane >> 4) * 8;
    const float* w = (l == 0) ? w1 : (l == 1) ? w2 : w3;
    unsigned short* wt = (l == 0) ? wp1 : (l == 1) ? wp2 : wp3;
    unsigned int wv[4];
#pragma unroll
    for (int j2 = 0; j2 < 4; ++j2) {
      const unsigned short e0 = f2bf(30.0f * w[(kb + 2 * j2) * 256 + feature]);
      const unsigned short e1 = f2bf(30.0f * w[(kb + 2 * j2 + 1) * 256 + feature]);
      wv[j2] = (unsigned int)e0 | ((unsigned int)e1 << 16);
    }
    uint4 v; v.x = wv[0]; v.y = wv[1]; v.z = wv[2]; v.w = wv[3];
    *(uint4*)(wt + tt * 8) = v;
    return;
  }
  if (bid < 1196) {                  // wp4: 4 blocks -> 1024 thr x 8 el = 8192
    const int t = (bid - 1192) * 256 + tid;
    const int lane = t & 63;
    const int kk = (t >> 6) & 7;
    const int i = (t >> 9) & 1;
    const int feature = i * 16 + (lane & 15);
    const int kb = kk * 32 + (lane >> 4) * 8;
    unsigned int wv[4];
#pragma unroll
    for (int j2 = 0; j2 < 4; ++j2) {
      const unsigned short e0 = (feature < 27) ? f2bf(w4[(kb + 2 * j2) * 27 + feature]) : (unsigned short)0;
      const unsigned short e1 = (feature < 27) ? f2bf(w4[(kb + 2 * j2 + 1) * 27 + feature]) : (unsigned short)0;
      wv[j2] = (unsigned int)e0 | ((unsigned int)e1 << 16);
    }
    uint4 v; v.x = wv[0]; v.y = wv[1]; v.z = wv[2]; v.w = wv[3];
    *(uint4*)(wp4 + t * 8) = v;
    return;
  }
  if (bid == 1196) {
    b0p[tid] = 30.0f * (b0[tid] + coord[2] * w0[576 * 256 + tid]);
  } else if (bid == 1197) {
    if (tid < 32) b4p[tid] = (tid < 27) ? b4[tid] : 0.0f;
  } else {
    const int l = bid - 1198;        // 0..2
    const float* bs = (l == 0) ? b1 : (l == 1) ? b2 : b3;
    float* bd = (l == 0) ? b1p : (l == 1) ? b2p : b3p;
    bd[tid] = 30.0f * bs[tid];
  }
}

// ---------------------------------------------------------------------------
// Fused MLP (ROUND-4 VERBATIM — best verified: 101.2us, MfmaUtil 40, zero
// spill).  Block = 64 pixels, 4 waves, H = 32KB in-place -> 3 blocks/CU
// (96KB LDS, 12 waves/CU).  __launch_bounds__(256,3): 168-reg budget/wave;
// acc=64 AGPR + ~84 arch VGPR.  No manual A double-buffer (round-2 spill
// lesson); no bar_lds/setprio (round-5: -12us); no px-half pipeline
// (round-6: -15us).  W0=30 pre-folded -> epilogue is sin(acc).
// H layout: px-major 512B/px, chunk c at px*512 + ((c^(px&7))<<4).
// Layer-0 patch: 3 rows x 66 px x 128B = 24.75KB aliases H.
// XCD-chunked swizzle: 2048 blocks %8==0 -> bijective.
// pat is plane-major: pat[g*131072 + p], g=0..26.
// ---------------------------------------------------------------------------
__device__ __forceinline__ void acc_init(floatx4 (&acc)[4][4],
                                         const float* __restrict__ bias,
                                         int wv, int lm, int q) {
#pragma unroll
  for (int i = 0; i < 4; ++i) {
    const float4 bv = *(const float4*)(bias + wv * 64 + i * 16 + q * 4);
    floatx4 a;
    a[0] = bv.x; a[1] = bv.y; a[2] = bv.z; a[3] = bv.w;
#pragma unroll
    for (int j = 0; j < 4; ++j) acc[i][j] = a;
  }
}

__device__ __forceinline__ void mid_K(floatx4 (&acc)[4][4], const char* H,
                                      const unsigned short* WT,
                                      int wv, int lm, int q, int ln16) {
  const char* a0 = (const char*)WT + wv * 32768 + ln16;
  const int l7 = lm & 7;
#pragma unroll
  for (int kk = 0; kk < 8; ++kk) {
    short8 af[4];
#pragma unroll
    for (int i = 0; i < 4; ++i)
      af[i] = *(const short8*)(a0 + ((i * 8 + kk) << 10));
#pragma unroll
    for (int j = 0; j < 4; ++j) {
      const int pp = j * 16 + lm;
      const int c = kk * 4 + q;
      const short8 bfr = *(const short8*)(H + pp * 512 + ((c ^ l7) << 4));
#pragma unroll
      for (int i = 0; i < 4; ++i)
        acc[i][j] = __builtin_amdgcn_mfma_f32_16x16x32_bf16(af[i], bfr, acc[i][j], 0, 0, 0);
    }
  }
}

__device__ __forceinline__ void epilogue(floatx4 (&acc)[4][4], char* Hout,
                                         int wv, int lm, int q) {
  const int l7 = lm & 7;
#pragma unroll
  for (int i = 0; i < 4; ++i) {
#pragma unroll
    for (int j = 0; j < 4; ++j) {
      unsigned int lo = (unsigned int)f2bf(__sinf(acc[i][j][0]))
                      | ((unsigned int)f2bf(__sinf(acc[i][j][1])) << 16);
      unsigned int hi = (unsigned int)f2bf(__sinf(acc[i][j][2]))
                      | ((unsigned int)f2bf(__sinf(acc[i][j][3])) << 16);
      const int pp = j * 16 + lm;
      const int c = wv * 8 + i * 2 + (q >> 1);
      uint2 v; v.x = lo; v.y = hi;
      *(uint2*)(Hout + pp * 512 + ((c ^ l7) << 4) + (q & 1) * 8) = v;
    }
  }
}

__global__ __launch_bounds__(256, 3) void k_fused(
    const unsigned short* __restrict__ X0,
    const unsigned short* __restrict__ wp0, const float* __restrict__ b0p,
    const unsigned short* __restrict__ wp1, const float* __restrict__ b1,
    const unsigned short* __restrict__ wp2, const float* __restrict__ b2,
    const unsigned short* __restrict__ wp3, const float* __restrict__ b3,
    const unsigned short* __restrict__ wp4, const float* __restrict__ b4p,
    float* __restrict__ pat) {
  __shared__ alignas(128) char H[32768];
  const int tid = threadIdx.x;
  const int bid = ((blockIdx.x & 7) << 8) + (blockIdx.x >> 3);  // XCD chunk
  const int pbase = bid * 64;
  const int bimg = pbase >> 16;
  const int y = (pbase >> 8) & 255;
  const int x0 = pbase & 255;  // 0, 64, 128 or 192
  const int lm = tid & 15;
  const int q = (tid & 63) >> 4;
  const int wv = tid >> 6;
  const int l7 = lm & 7;
  const int ln16 = (tid & 63) * 16;

  // ---- stage 3x66 pixel patch (1584 chunks of 16B, swizzled by rp&7) ----
#pragma unroll
  for (int iter = 0; iter < 7; ++iter) {
    const int ci = iter * 256 + tid;
    if (ci < 1584) {
      const int rp = ci >> 3;
      const int row = rp / 66;
      const int col = rp - row * 66;
      int gy = y + row - 1;
      int gx = x0 + col - 1;
      gy = gy < 0 ? 0 : (gy > 255 ? 255 : gy);
      gx = gx < 0 ? 0 : (gx > 255 ? 255 : gx);
      const int gch = (ci & 7) ^ (rp & 7);
      const int p = (bimg << 16) + (gy << 8) + gx;
      gld16((const char*)X0 + (int64_t)p * 128 + gch * 16, H + ci * 16);
    }
  }
  __syncthreads();
  // zero out-of-range pixels (image edges)
#pragma unroll
  for (int iter = 0; iter < 7; ++iter) {
    const int ci = iter * 256 + tid;
    if (ci < 1584) {
      const int rp = ci >> 3;
      const int row = rp / 66;
      const int col = rp - row * 66;
      const int gy = y + row - 1;
      const int gx = x0 + col - 1;
      if ((unsigned)gy >= 256u || (unsigned)gx >= 256u) {
        uint4 z; z.x = 0; z.y = 0; z.z = 0; z.w = 0;
        *(uint4*)(H + ci * 16) = z;
      }
    }
  }
  __syncthreads();

  floatx4 acc[4][4];
  acc_init(acc, b0p, wv, lm, q);

  // ---- layer 0: implicit 3x3 conv, 18 (tap,kk) steps ----
  {
    const char* a0 = (const char*)wp0 + wv * 73728 + ln16;
#pragma unroll
    for (int t = 0; t < 18; ++t) {
      short8 af[4];
#pragma unroll
      for (int i = 0; i < 4; ++i)
        af[i] = *(const short8*)(a0 + ((i * 18 + t) << 10));
      const int tap = t >> 1;
      const int kk = t & 1;
      const int dyr = tap / 3;
      const int dxr = tap - dyr * 3;
      const int rpb = dyr * 66 + dxr;
#pragma unroll
      for (int j = 0; j < 4; ++j) {
        const int rp = rpb + j * 16 + lm;
        const int c = kk * 4 + q;
        const short8 bfr = *(const short8*)(H + rp * 128 + ((c ^ (rp & 7)) << 4));
#pragma unroll
        for (int i = 0; i < 4; ++i)
          acc[i][j] = __builtin_amdgcn_mfma_f32_16x16x32_bf16(af[i], bfr, acc[i][j], 0, 0, 0);
      }
    }
  }
  __syncthreads();             // all waves done reading patch
  epilogue(acc, H, wv, lm, q);
  __syncthreads();

  // ---- layers 1..3: in-place H ----
  const unsigned short* WTs[3] = {wp1, wp2, wp3};
  const float* Bs[3] = {b1, b2, b3};
#pragma unroll 1
  for (int l = 0; l < 3; ++l) {
    acc_init(acc, Bs[l], wv, lm, q);
    mid_K(acc, H, WTs[l], wv, lm, q, ln16);
    __syncthreads();           // all reads of H done
    epilogue(acc, H, wv, lm, q);
    __syncthreads();
  }

  // ---- layer 4: H -> pat planes (each wave: 16-px strip x 32 features) ----
  {
    floatx4 a4[2];
#pragma unroll
    for (int i = 0; i < 2; ++i) {
      const float4 bb = *(const float4*)(b4p + i * 16 + q * 4);
      floatx4 a;
      a[0] = bb.x; a[1] = bb.y; a[2] = bb.z; a[3] = bb.w;
      a4[i] = a;
    }
    const char* aw = (const char*)wp4 + ln16;
    const int pp = wv * 16 + lm;
#pragma unroll
    for (int kk = 0; kk < 8; ++kk) {
      const short8 af0 = *(const short8*)(aw + (kk << 10));
      const short8 af1 = *(const short8*)(aw + ((8 + kk) << 10));
      const int c = kk * 4 + q;
      const short8 bfr = *(const short8*)(H + pp * 512 + ((c ^ l7) << 4));
      a4[0] = __builtin_amdgcn_mfma_f32_16x16x32_bf16(af0, bfr, a4[0], 0, 0, 0);
      a4[1] = __builtin_amdgcn_mfma_f32_16x16x32_bf16(af1, bfr, a4[1], 0, 0, 0);
    }
#pragma unroll
    for (int i = 0; i < 2; ++i)
#pragma unroll
      for (int r = 0; r < 4; ++r) {
        const int g = i * 16 + q * 4 + r;
        if (g < 27)
          pat[g * 131072 + pbase + wv * 16 + lm] = a4[i][r];
      }
  }
}

// fold3 (plane-major pat): out[b][c][y][x] =
//   sum_{i,j} pat[(c*9+i*3+j)*131072 + b*65536 + (y+1-i)*256 + (x+1-j)]
__global__ __launch_bounds__(256) void k_fold(const float* __restrict__ pat,
                                              float* __restrict__ out) {
  const int e = blockIdx.x * 256 + threadIdx.x;  // < 393216
  const int x = e & 255;
  const int y = (e >> 8) & 255;
  const int bc = e >> 16;
  const int c = bc % 3;
  const int b = bc / 3;
  float s = 0.0f;
#pragma unroll
  for (int i = 0; i < 3; ++i) {
    const int yy = y + 1 - i;
    if (yy < 0 || yy > 255) continue;
#pragma unroll
    for (int j = 0; j < 3; ++j) {
      const int xx = x + 1 - j;
      if (xx < 0 || xx > 255) continue;
      s += pat[(c * 9 + i * 3 + j) * 131072 + (b << 16) + yy * 256 + xx];
    }
  }
  out[e] = s;
}

extern "C" void kernel_launch(void* const* d_in, const int* in_sizes, int n_in,
                              void* d_out, int out_size, void* d_ws, size_t ws_size,
                              hipStream_t stream) {
  const float* feat  = (const float*)d_in[0];
  const float* coord = (const float*)d_in[1];
  const float* w0 = (const float*)d_in[2];
  const float* b0 = (const float*)d_in[3];
  const float* w1 = (const float*)d_in[4];
  const float* b1 = (const float*)d_in[5];
  const float* w2 = (const float*)d_in[6];
  const float* b2 = (const float*)d_in[7];
  const float* w3 = (const float*)d_in[8];
  const float* b3 = (const float*)d_in[9];
  const float* w4 = (const float*)d_in[10];
  const float* b4 = (const float*)d_in[11];

  char* ws = (char*)d_ws;
  unsigned short* X0  = (unsigned short*)(ws);                 // 16.78 MB
  float*          pat = (float*)(ws + 16777216);               // 14.16 MB (27 planes)
  float*          b1p = (float*)(ws + 30932992);               // in pat..wp0 slack
  float*          b2p = (float*)(ws + 30934016);
  float*          b3p = (float*)(ws + 30935040);
  unsigned short* wp0 = (unsigned short*)(ws + 33554432);      // 294912 B
  unsigned short* wp1 = (unsigned short*)(ws + 33849344);      // 131072 B
  unsigned short* wp2 = (unsigned short*)(ws + 33980416);
  unsigned short* wp3 = (unsigned short*)(ws + 34111488);
  unsigned short* wp4 = (unsigned short*)(ws + 34242560);      // 16384 B
  float*          b0p = (float*)(ws + 34258944);               // 1024 B
  float*          b4p = (float*)(ws + 34259968);               // 128 B
  float* out = (float*)d_out;

  hipLaunchKernelGGL(k_pre, dim3(1201), dim3(256), 0, stream,
                     feat, w0, b0, w1, b1, w2, b2, w3, b3, w4, b4, coord,
                     X0, wp0, wp1, wp2, wp3, wp4, b0p, b4p, b1p, b2p, b3p);
  hipLaunchKernelGGL(k_fused, dim3(2048), dim3(256), 0, stream,
                     X0, wp0, b0p, wp1, b1p, wp2, b2p, wp3, b3p, wp4, b4p, pat);
  hipLaunchKernelGGL(k_fold, dim3(1536), dim3(256), 0, stream, pat, out);
}

// Round 9
// 190.503 us; speedup vs baseline: 1.0792x; 1.0399x over previous
//
#include <hip/hip_runtime.h>
#include <stdint.h>

typedef __attribute__((ext_vector_type(8))) short short8;
typedef __attribute__((ext_vector_type(4))) float floatx4;

#define AS1 __attribute__((address_space(1)))
#define AS3 __attribute__((address_space(3)))

__device__ __forceinline__ void gld16(const void* g, void* l) {
  __builtin_amdgcn_global_load_lds((AS1 const void*)g, (AS3 void*)l, 16, 0, 0);
}

__device__ __forceinline__ unsigned short f2bf(float f) {
  unsigned int u = __float_as_uint(f);
  return (unsigned short)((u + 0x7fffu + ((u >> 16) & 1u)) >> 16);
}

// ---------------------------------------------------------------------------
// k_pre (round-4 version, verified absmax 0.00293):
// blocks [0,512) = featT (X0[p][c] = bf16 feat, pixel-major 128B rows);
// blocks [512,...) = weight packing into MFMA A-fragment order.
// W0=30 FOLDED into wp0..wp3 and b0p/b1p/b2p/b3p (sin(30*(Wx+b)) ==
// sin((30W)x + 30b)) -> epilogue computes sin(acc) directly.
// Packed: per (panel of 16 out-features, step) one 1KB chunk, element (lane,j)
// at chunk + lane*16 + j*2 -> feature = panel*16 + (lane&15),
// k = kk*32 + (lane>>4)*8 + j.  Every af load = coalesced 1KB burst.
// wp0: 16 panels x 18 steps(tap*2+kk);  wp{1,2,3}: 16 panels x 8 kk;
// wp4: 2 panels x 8 kk (feature>=27 -> 0, unscaled).
// NOTE round-8 lesson: v_cvt_pk_bf16_f32 is NOT RNE-equivalent to f2bf
// (absmax 0.29) — manual pack only.
// ---------------------------------------------------------------------------
__global__ __launch_bounds__(256) void k_pre(
    const float* __restrict__ feat,
    const float* __restrict__ w0, const float* __restrict__ b0,
    const float* __restrict__ w1, const float* __restrict__ b1,
    const float* __restrict__ w2, const float* __restrict__ b2,
    const float* __restrict__ w3, const float* __restrict__ b3,
    const float* __restrict__ w4, const float* __restrict__ b4,
    const float* __restrict__ coord,
    unsigned short* __restrict__ X0,
    unsigned short* __restrict__ wp0, unsigned short* __restrict__ wp1,
    unsigned short* __restrict__ wp2, unsigned short* __restrict__ wp3,
    unsigned short* __restrict__ wp4, float* __restrict__ b0p,
    float* __restrict__ b4p, float* __restrict__ b1p,
    float* __restrict__ b2p, float* __restrict__ b3p) {
  const int bid = blockIdx.x;
  const int tid = threadIdx.x;
  if (bid < 512) {
    const int p = bid * 256 + tid;
    const int b = p >> 16;
    const int off = p & 65535;
    const float* src = feat + ((int64_t)b << 22) + off;
    unsigned int tw[32];
#pragma unroll
    for (int c = 0; c < 32; ++c) {
      float lo = src[(int64_t)(2 * c) << 16];
      float hi = src[(int64_t)(2 * c + 1) << 16];
      tw[c] = (unsigned int)f2bf(lo) | ((unsigned int)f2bf(hi) << 16);
    }
    uint4* dst = (uint4*)(X0 + (int64_t)p * 64);
#pragma unroll
    for (int k = 0; k < 8; ++k) {
      uint4 v;
      v.x = tw[4 * k]; v.y = tw[4 * k + 1]; v.z = tw[4 * k + 2]; v.w = tw[4 * k + 3];
      dst[k] = v;
    }
    return;
  }
  const int e = (bid - 512) * 256 + tid;
  if (e < 147456) {
    const int j = e & 7, lane = (e >> 3) & 63, r = e >> 9;
    const int kk = r & 1, s = r >> 1;
    const int tap = s % 9, panel = s / 9;
    const int feature = panel * 16 + (lane & 15);
    const int c = kk * 32 + (lane >> 4) * 8 + j;
    wp0[e] = f2bf(30.0f * w0[(c * 9 + tap) * 256 + feature]);
  } else if (e < 344064) {
    const int e2 = e - 147456;
    const int l = e2 >> 16;
    const int u = e2 & 65535;
    const int j = u & 7, lane = (u >> 3) & 63, kk = (u >> 9) & 7, panel = (u >> 12) & 15;
    const int feature = panel * 16 + (lane & 15);
    const int k = kk * 32 + (lane >> 4) * 8 + j;
    const float* w = (l == 0) ? w1 : (l == 1) ? w2 : w3;
    unsigned short* wt = (l == 0) ? wp1 : (l == 1) ? wp2 : wp3;
    wt[u] = f2bf(30.0f * w[k * 256 + feature]);
  } else if (e < 352256) {
    const int u = e - 344064;
    const int j = u & 7, lane = (u >> 3) & 63, kk = (u >> 9) & 7, i = (u >> 12) & 1;
    const int feature = i * 16 + (lane & 15);
    const int k = kk * 32 + (lane >> 4) * 8 + j;
    wp4[u] = (feature < 27) ? f2bf(w4[k * 27 + feature]) : (unsigned short)0;
  } else if (e < 352512) {
    const int n = e - 352256;
    b0p[n] = 30.0f * (b0[n] + coord[2] * w0[576 * 256 + n]);
  } else if (e < 352544) {
    const int n = e - 352512;
    b4p[n] = (n < 27) ? b4[n] : 0.0f;
  } else if (e < 353312) {
    const int n = e - 352544;  // 0..767
    const int l = n >> 8;
    const int m = n & 255;
    const float* bs = (l == 0) ? b1 : (l == 1) ? b2 : b3;
    float* bd = (l == 0) ? b1p : (l == 1) ? b2p : b3p;
    bd[m] = 30.0f * bs[m];
  }
}

// ---------------------------------------------------------------------------
// Fused MLP — ROUND-0 GEOMETRY (best verified k_fused: 99.36us): block = 128
// pixels (half image row), 4 waves, H = 64KB in-place, 2 blocks/CU
// ((256,2): 256-reg budget/wave -> acc 64 AGPR + ~128 arch VGPR, no spill),
// manual afn[4] A-prefetch (fits at this budget; spilled only at (256,3/4)).
// Composed with round-4's W0-folded weights -> epilogue is sin(acc).
// Session ledger: (256,4) spills (r1); (256,3)+64px = 100.4 (r4);
// bar_lds/setprio -12us (r5); px-half pipeline -15us (r6); k_pre coalesce
// neutral (r7); cvt_pk wrong numerics (r8).  MfmaUtil pinned ~40% across all.
// H layout: px-major 512B/px, chunk c at px*512 + ((c^(px&7))<<4).
// Layer-0 patch: 3 rows x 130 px x 128B = 48.75KB aliases H.
// XCD-chunked swizzle: 1024 blocks %8==0 -> bijective.
// pat is plane-major: pat[g*131072 + p], g=0..26.
// ---------------------------------------------------------------------------
__device__ __forceinline__ void acc_init(floatx4 (&acc)[4][8],
                                         const float* __restrict__ bias,
                                         int wv, int lm, int q) {
#pragma unroll
  for (int i = 0; i < 4; ++i) {
    const float4 bv = *(const float4*)(bias + wv * 64 + i * 16 + q * 4);
    floatx4 a;
    a[0] = bv.x; a[1] = bv.y; a[2] = bv.z; a[3] = bv.w;
#pragma unroll
    for (int j = 0; j < 8; ++j) acc[i][j] = a;
  }
}

__device__ __forceinline__ void mid_K(floatx4 (&acc)[4][8], const char* H,
                                      const unsigned short* WT,
                                      int wv, int lm, int q, int ln16) {
  const char* a0 = (const char*)WT + wv * 32768 + ln16;
  const int l7 = lm & 7;
  short8 af[4];
#pragma unroll
  for (int i = 0; i < 4; ++i) af[i] = *(const short8*)(a0 + ((i * 8) << 10));
#pragma unroll
  for (int kk = 0; kk < 8; ++kk) {
    short8 afn[4];
    if (kk < 7) {
#pragma unroll
      for (int i = 0; i < 4; ++i)
        afn[i] = *(const short8*)(a0 + ((i * 8 + kk + 1) << 10));
    }
#pragma unroll
    for (int j = 0; j < 8; ++j) {
      const int pp = j * 16 + lm;
      const int c = kk * 4 + q;
      const short8 bfr = *(const short8*)(H + pp * 512 + ((c ^ l7) << 4));
#pragma unroll
      for (int i = 0; i < 4; ++i)
        acc[i][j] = __builtin_amdgcn_mfma_f32_16x16x32_bf16(af[i], bfr, acc[i][j], 0, 0, 0);
    }
    if (kk < 7) {
#pragma unroll
      for (int i = 0; i < 4; ++i) af[i] = afn[i];
    }
  }
}

__device__ __forceinline__ void epilogue(floatx4 (&acc)[4][8], char* Hout,
                                         int wv, int lm, int q) {
  const int l7 = lm & 7;
#pragma unroll
  for (int i = 0; i < 4; ++i) {
#pragma unroll
    for (int j = 0; j < 8; ++j) {
      unsigned int lo = (unsigned int)f2bf(__sinf(acc[i][j][0]))
                      | ((unsigned int)f2bf(__sinf(acc[i][j][1])) << 16);
      unsigned int hi = (unsigned int)f2bf(__sinf(acc[i][j][2]))
                      | ((unsigned int)f2bf(__sinf(acc[i][j][3])) << 16);
      const int pp = j * 16 + lm;
      const int c = wv * 8 + i * 2 + (q >> 1);
      uint2 v; v.x = lo; v.y = hi;
      *(uint2*)(Hout + pp * 512 + ((c ^ l7) << 4) + (q & 1) * 8) = v;
    }
  }
}

__global__ __launch_bounds__(256, 2) void k_fused(
    const unsigned short* __restrict__ X0,
    const unsigned short* __restrict__ wp0, const float* __restrict__ b0p,
    const unsigned short* __restrict__ wp1, const float* __restrict__ b1,
    const unsigned short* __restrict__ wp2, const float* __restrict__ b2,
    const unsigned short* __restrict__ wp3, const float* __restrict__ b3,
    const unsigned short* __restrict__ wp4, const float* __restrict__ b4p,
    float* __restrict__ pat) {
  __shared__ alignas(128) char H[65536];
  const int tid = threadIdx.x;
  const int bid = ((blockIdx.x & 7) << 7) + (blockIdx.x >> 3);  // XCD chunk
  const int pbase = bid * 128;
  const int bimg = pbase >> 16;
  const int y = (pbase >> 8) & 255;
  const int x0 = pbase & 255;  // 0 or 128
  const int lm = tid & 15;
  const int q = (tid & 63) >> 4;
  const int wv = tid >> 6;
  const int l7 = lm & 7;
  const int ln16 = (tid & 63) * 16;

  // ---- stage 3x130 pixel patch (3120 chunks of 16B, swizzled by rp&7) ----
#pragma unroll
  for (int iter = 0; iter < 13; ++iter) {
    const int ci = iter * 256 + tid;
    if (ci < 3120) {
      const int rp = ci >> 3;
      const int row = rp / 130;
      const int col = rp - row * 130;
      int gy = y + row - 1;
      int gx = x0 + col - 1;
      gy = gy < 0 ? 0 : (gy > 255 ? 255 : gy);
      gx = gx < 0 ? 0 : (gx > 255 ? 255 : gx);
      const int gch = (ci & 7) ^ (rp & 7);
      const int p = (bimg << 16) + (gy << 8) + gx;
      gld16((const char*)X0 + (int64_t)p * 128 + gch * 16, H + ci * 16);
    }
  }
  __syncthreads();
  // zero out-of-range pixels (image edges)
#pragma unroll
  for (int iter = 0; iter < 13; ++iter) {
    const int ci = iter * 256 + tid;
    if (ci < 3120) {
      const int rp = ci >> 3;
      const int row = rp / 130;
      const int col = rp - row * 130;
      const int gy = y + row - 1;
      const int gx = x0 + col - 1;
      if ((unsigned)gy >= 256u || (unsigned)gx >= 256u) {
        uint4 z; z.x = 0; z.y = 0; z.z = 0; z.w = 0;
        *(uint4*)(H + ci * 16) = z;
      }
    }
  }
  __syncthreads();

  floatx4 acc[4][8];
  acc_init(acc, b0p, wv, lm, q);

  // ---- layer 0: implicit 3x3 conv, 18 (tap,kk) steps, af pipelined ----
  {
    const char* a0 = (const char*)wp0 + wv * 73728 + ln16;
    short8 af[4];
#pragma unroll
    for (int i = 0; i < 4; ++i) af[i] = *(const short8*)(a0 + ((i * 18) << 10));
#pragma unroll
    for (int t = 0; t < 18; ++t) {
      const int tap = t >> 1;
      const int kk = t & 1;
      short8 afn[4];
      if (t < 17) {
#pragma unroll
        for (int i = 0; i < 4; ++i)
          afn[i] = *(const short8*)(a0 + ((i * 18 + t + 1) << 10));
      }
      const int dyr = tap / 3;
      const int dxr = tap - dyr * 3;
      const int rpb = dyr * 130 + dxr;
#pragma unroll
      for (int j = 0; j < 8; ++j) {
        const int rp = rpb + j * 16 + lm;
        const int c = kk * 4 + q;
        const short8 bfr = *(const short8*)(H + rp * 128 + ((c ^ (rp & 7)) << 4));
#pragma unroll
        for (int i = 0; i < 4; ++i)
          acc[i][j] = __builtin_amdgcn_mfma_f32_16x16x32_bf16(af[i], bfr, acc[i][j], 0, 0, 0);
      }
      if (t < 17) {
#pragma unroll
        for (int i = 0; i < 4; ++i) af[i] = afn[i];
      }
    }
  }
  __syncthreads();             // all waves done reading patch
  epilogue(acc, H, wv, lm, q);
  __syncthreads();

  // ---- layers 1..3: in-place H ----
  const unsigned short* WTs[3] = {wp1, wp2, wp3};
  const float* Bs[3] = {b1, b2, b3};
#pragma unroll 1
  for (int l = 0; l < 3; ++l) {
    acc_init(acc, Bs[l], wv, lm, q);
    mid_K(acc, H, WTs[l], wv, lm, q, ln16);
    __syncthreads();           // all reads of H done
    epilogue(acc, H, wv, lm, q);
    __syncthreads();
  }

  // ---- layer 4: H -> pat planes (each wave: 32-px strip x 32 features) ----
  {
    floatx4 a4[2][2];
#pragma unroll
    for (int i = 0; i < 2; ++i) {
      const float4 bb = *(const float4*)(b4p + i * 16 + q * 4);
      floatx4 a;
      a[0] = bb.x; a[1] = bb.y; a[2] = bb.z; a[3] = bb.w;
      a4[i][0] = a; a4[i][1] = a;
    }
    const char* aw = (const char*)wp4 + ln16;
#pragma unroll
    for (int kk = 0; kk < 8; ++kk) {
      const short8 af0 = *(const short8*)(aw + (kk << 10));
      const short8 af1 = *(const short8*)(aw + ((8 + kk) << 10));
#pragma unroll
      for (int jj = 0; jj < 2; ++jj) {
        const int pp = wv * 32 + jj * 16 + lm;
        const int c = kk * 4 + q;
        const short8 bfr = *(const short8*)(H + pp * 512 + ((c ^ l7) << 4));
        a4[0][jj] = __builtin_amdgcn_mfma_f32_16x16x32_bf16(af0, bfr, a4[0][jj], 0, 0, 0);
        a4[1][jj] = __builtin_amdgcn_mfma_f32_16x16x32_bf16(af1, bfr, a4[1][jj], 0, 0, 0);
      }
    }
#pragma unroll
    for (int i = 0; i < 2; ++i)
#pragma unroll
      for (int jj = 0; jj < 2; ++jj)
#pragma unroll
        for (int r = 0; r < 4; ++r) {
          const int g = i * 16 + q * 4 + r;
          if (g < 27)
            pat[g * 131072 + pbase + wv * 32 + jj * 16 + lm] = a4[i][jj][r];
        }
  }
}

// fold3 (plane-major pat): out[b][c][y][x] =
//   sum_{i,j} pat[(c*9+i*3+j)*131072 + b*65536 + (y+1-i)*256 + (x+1-j)]
__global__ __launch_bounds__(256) void k_fold(const float* __restrict__ pat,
                                              float* __restrict__ out) {
  const int e = blockIdx.x * 256 + threadIdx.x;  // < 393216
  const int x = e & 255;
  const int y = (e >> 8) & 255;
  const int bc = e >> 16;
  const int c = bc % 3;
  const int b = bc / 3;
  float s = 0.0f;
#pragma unroll
  for (int i = 0; i < 3; ++i) {
    const int yy = y + 1 - i;
    if (yy < 0 || yy > 255) continue;
#pragma unroll
    for (int j = 0; j < 3; ++j) {
      const int xx = x + 1 - j;
      if (xx < 0 || xx > 255) continue;
      s += pat[(c * 9 + i * 3 + j) * 131072 + (b << 16) + yy * 256 + xx];
    }
  }
  out[e] = s;
}

extern "C" void kernel_launch(void* const* d_in, const int* in_sizes, int n_in,
                              void* d_out, int out_size, void* d_ws, size_t ws_size,
                              hipStream_t stream) {
  const float* feat  = (const float*)d_in[0];
  const float* coord = (const float*)d_in[1];
  const float* w0 = (const float*)d_in[2];
  const float* b0 = (const float*)d_in[3];
  const float* w1 = (const float*)d_in[4];
  const float* b1 = (const float*)d_in[5];
  const float* w2 = (const float*)d_in[6];
  const float* b2 = (const float*)d_in[7];
  const float* w3 = (const float*)d_in[8];
  const float* b3 = (const float*)d_in[9];
  const float* w4 = (const float*)d_in[10];
  const float* b4 = (const float*)d_in[11];

  char* ws = (char*)d_ws;
  unsigned short* X0  = (unsigned short*)(ws);                 // 16.78 MB
  float*          pat = (float*)(ws + 16777216);               // 14.16 MB (27 planes)
  float*          b1p = (float*)(ws + 30932992);               // in pat..wp0 slack
  float*          b2p = (float*)(ws + 30934016);
  float*          b3p = (float*)(ws + 30935040);
  unsigned short* wp0 = (unsigned short*)(ws + 33554432);      // 294912 B
  unsigned short* wp1 = (unsigned short*)(ws + 33849344);      // 131072 B
  unsigned short* wp2 = (unsigned short*)(ws + 33980416);
  unsigned short* wp3 = (unsigned short*)(ws + 34111488);
  unsigned short* wp4 = (unsigned short*)(ws + 34242560);      // 16384 B
  float*          b0p = (float*)(ws + 34258944);               // 1024 B
  float*          b4p = (float*)(ws + 34259968);               // 128 B
  float* out = (float*)d_out;

  hipLaunchKernelGGL(k_pre, dim3(1893), dim3(256), 0, stream,
                     feat, w0, b0, w1, b1, w2, b2, w3, b3, w4, b4, coord,
                     X0, wp0, wp1, wp2, wp3, wp4, b0p, b4p, b1p, b2p, b3p);
  hipLaunchKernelGGL(k_fused, dim3(1024), dim3(256), 0, stream,
                     X0, wp0, b0p, wp1, b1p, wp2, b2p, wp3, b3p, wp4, b4p, pat);
  hipLaunchKernelGGL(k_fold, dim3(1536), dim3(256), 0, stream, pat, out);
}